// Round 2
// baseline (633.658 us; speedup 1.0000x reference)
//
#include <hip/hip_runtime.h>
#include <cstdint>
#include <cstddef>

#define BATCH 256
#define ED 128
#define NC 32
#define HO 6
#define WO 14
#define FEAT 2688          // 32*6*14
#define HID 256
#define NE 40943
#define EPS 1e-5f
#define W2COLS 344064      // FEAT*128

typedef __attribute__((ext_vector_type(4))) float f32x4;
typedef __attribute__((ext_vector_type(8))) short short8;

__device__ __forceinline__ ushort f2bf(float f) {
    uint32_t u = __builtin_bit_cast(uint32_t, f);
    u = (u + 0x7FFFu + ((u >> 16) & 1u)) >> 16;
    return (ushort)u;
}

// Barrier WITHOUT the compiler's vmcnt(0) drain. Safe in k4: no global_load_lds
// is used (all VMEM loads target private VGPRs), so only LDS ops need draining
// for cross-wave visibility.
__device__ __forceinline__ void bar_nd() {
    asm volatile("s_waitcnt lgkmcnt(0)" ::: "memory");
    __builtin_amdgcn_s_barrier();
    asm volatile("" ::: "memory");
}

// ---------------- K0: bn0 stats (global mean/var of gathered E1) -----------
__global__ void k0_bn0(const int* __restrict__ e1, const float* __restrict__ emb,
                       float* __restrict__ stats) {
    int t = threadIdx.x;                  // 1024 threads
    int i = t >> 2, p = (t & 3) * 32;
    const float* row = emb + (size_t)e1[i] * ED + p;
    float a = 0.f, b = 0.f;
#pragma unroll
    for (int q = 0; q < 32; ++q) { float v = row[q]; a += v; b += v * v; }
#pragma unroll
    for (int off = 32; off > 0; off >>= 1) {
        a += __shfl_down(a, off, 64);
        b += __shfl_down(b, off, 64);
    }
    __shared__ float pa[16], pb[16];
    int w = t >> 6, lane = t & 63;
    if (lane == 0) { pa[w] = a; pb[w] = b; }
    __syncthreads();
    if (t == 0) {
        float sa = 0.f, sb = 0.f;
#pragma unroll
        for (int q = 0; q < 16; ++q) { sa += pa[q]; sb += pb[q]; }
        float m = sa / 32768.f;
        float v = sb / 32768.f - m * m;
        stats[0] = m;
        stats[1] = rsqrtf(v + EPS);
    }
}

// ---------------- K1: CPG hidden layers H[head][i][u] = relu(R@w1) ---------
// i-tiled: 64 blocks = head(4) x itile(16). Each block stages 16 R rows in
// LDS and streams w1 once -> w1 traffic 134 MB -> 8.4 MB.
__global__ __launch_bounds__(256) void k1_hidden(const int* __restrict__ r,
                          const float* __restrict__ rel,
                          const float* __restrict__ w1a, const float* __restrict__ w1b,
                          const float* __restrict__ w1c, const float* __restrict__ w1d,
                          float* __restrict__ H) {
    int head = blockIdx.x >> 4;
    int it = blockIdx.x & 15;      // i = it*16 + ii
    int u = threadIdx.x;           // 256 threads
    __shared__ __align__(16) float Rs[16][128];
    for (int idx = u; idx < 2048; idx += 256) {
        int ii = idx >> 7, d = idx & 127;
        Rs[ii][d] = rel[(size_t)r[it * 16 + ii] * 128 + d];
    }
    __syncthreads();
    const float* w1 = head == 0 ? w1a : head == 1 ? w1b : head == 2 ? w1c : w1d;
    float acc[16];
#pragma unroll
    for (int ii = 0; ii < 16; ++ii) acc[ii] = 0.f;
    for (int d4 = 0; d4 < 32; ++d4) {
        int d = d4 * 4;
        float w0 = w1[(d + 0) * 256 + u];
        float w1v = w1[(d + 1) * 256 + u];
        float w2v = w1[(d + 2) * 256 + u];
        float w3v = w1[(d + 3) * 256 + u];
#pragma unroll
        for (int ii = 0; ii < 16; ++ii) {
            f32x4 rv = *(const f32x4*)&Rs[ii][d];
            acc[ii] = fmaf(rv[0], w0, fmaf(rv[1], w1v,
                      fmaf(rv[2], w2v, fmaf(rv[3], w3v, acc[ii]))));
        }
    }
#pragma unroll
    for (int ii = 0; ii < 16; ++ii)
        H[((size_t)head * 256 + it * 16 + ii) * 256 + u] = fmaxf(acc[ii], 0.f);
}

// ---------------- K2: small CPG head outputs (filt, cbias, fcb) ------------
// i-tiled: 32 blocks of 8 samples. H slabs (heads 0,1,3) staged in LDS once;
// w2 traffic 117 MB -> 15 MB.
__global__ __launch_bounds__(512) void k2_heads(const float* __restrict__ H,
                         const float* __restrict__ w2f, const float* __restrict__ w2b,
                         const float* __restrict__ w2fcb,
                         float* __restrict__ filt, float* __restrict__ cbias,
                         float* __restrict__ fcb) {
    int it = blockIdx.x;           // i = it*8 + ii
    int t = threadIdx.x;           // 512 threads
    __shared__ __align__(16) float Hs[3][8][256];   // 24 KB
    for (int idx = t; idx < 3 * 8 * 256; idx += 512) {
        int hh = idx >> 11, rem = idx & 2047, ii = rem >> 8, uu = rem & 255;
        int head = hh + (hh == 2);        // 0,1,3
        Hs[hh][ii][uu] = H[((size_t)head * 256 + it * 8 + ii) * 256 + uu];
    }
    __syncthreads();
    int hh, o, st;
    const float* w2;
    if (t < 288)      { hh = 0; o = t;       st = 288; w2 = w2f; }
    else if (t < 320) { hh = 1; o = t - 288; st = 32;  w2 = w2b; }
    else if (t < 448) { hh = 2; o = t - 320; st = 128; w2 = w2fcb; }
    else              { hh = 0; o = 0;       st = 288; w2 = w2f; }
    const float* wp = w2 + o;
    float acc[8];
#pragma unroll
    for (int ii = 0; ii < 8; ++ii) acc[ii] = 0.f;
    for (int u4 = 0; u4 < 64; ++u4) {
        int uu = u4 * 4;
        float w0 = wp[(uu + 0) * st];
        float w1v = wp[(uu + 1) * st];
        float w2v = wp[(uu + 2) * st];
        float w3v = wp[(uu + 3) * st];
#pragma unroll
        for (int ii = 0; ii < 8; ++ii) {
            f32x4 hv = *(const f32x4*)&Hs[hh][ii][uu];
            acc[ii] = fmaf(hv[0], w0, fmaf(hv[1], w1v,
                      fmaf(hv[2], w2v, fmaf(hv[3], w3v, acc[ii]))));
        }
    }
    if (t < 288) {
#pragma unroll
        for (int ii = 0; ii < 8; ++ii) filt[(it * 8 + ii) * 288 + o] = acc[ii];
    } else if (t < 320) {
#pragma unroll
        for (int ii = 0; ii < 8; ++ii) cbias[(it * 8 + ii) * 32 + o] = acc[ii];
    } else if (t < 448) {
#pragma unroll
        for (int ii = 0; ii < 8; ++ii) fcb[(it * 8 + ii) * 128 + o] = acc[ii];
    }
}

// ---------------- K3: per-sample conv + bias + relu -> Xc (bf16) -----------
__global__ void k3_conv(const int* __restrict__ e1, const float* __restrict__ emb,
                        const float* __restrict__ stats, const float* __restrict__ filt,
                        const float* __restrict__ cbias, ushort* __restrict__ Xc) {
    int i = blockIdx.x, t = threadIdx.x;   // 256 threads
    __shared__ float x[128], f[288], cb[32];
    float mean = stats[0], rstd = stats[1];
    if (t < 128) x[t] = (emb[(size_t)e1[i] * 128 + t] - mean) * rstd;
    if (t < 32) cb[t] = cbias[i * 32 + t];
    for (int o = t; o < 288; o += 256) f[o] = filt[i * 288 + o];
    __syncthreads();
    for (int o = t; o < FEAT; o += 256) {
        int c = o / 84, rem = o % 84;      // 84 = 6*14
        int y = rem / 14, xw = rem % 14;
        float acc = cb[c];
        const float* fc = &f[c * 9];
#pragma unroll
        for (int dy = 0; dy < 3; ++dy)
#pragma unroll
            for (int dx = 0; dx < 3; ++dx)
                acc += x[(y + dy) * 16 + (xw + dx)] * fc[dy * 3 + dx];
        Xc[(size_t)i * FEAT + o] = f2bf(fmaxf(acc, 0.f));
    }
}

// ---------------- K4: big batched GEMM  T2[i,h,k] = sum_j Xc[i,j]*W2[h,j,k] --
// One block per h (256 blocks); W2 row streamed from HBM exactly once.
// 64-j tiles (42 steps), LDS double-buffer, ONE no-drain barrier per step,
// depth-2 register prefetch so 32 KB/block stays in flight continuously.
// Output written TRANSPOSED [i][h][k] so K5 can stream contiguously.
__global__ __launch_bounds__(512, 2) void k4_gemm(const ushort* __restrict__ Xc,
                                                  const float* __restrict__ W2,
                                                  float* __restrict__ T2) {
    int h = blockIdx.x;
    int tid = threadIdx.x, lane = tid & 63, wave = tid >> 6;   // 8 waves
    int l15 = lane & 15, l4 = lane >> 4;
    __shared__ __align__(16) ushort Bt[2][128 * 72];   // [buf][k=128][j=64 +8 pad]
    const float* Brow = W2 + (size_t)h * W2COLS;

    int kk = tid & 127;        // k index this thread stages
    int jg = tid >> 7;         // j-group (0..3): j_rel = jg*16 .. +16

    f32x4 acc[2][8];
#pragma unroll
    for (int mt = 0; mt < 2; ++mt)
#pragma unroll
        for (int nt = 0; nt < 8; ++nt)
#pragma unroll
            for (int q = 0; q < 4; ++q) acc[mt][nt][q] = 0.f;

    const float* base0 = Brow + (size_t)jg * 16 * 128 + kk;

#define K4_ISSUE(P, TILE)                                                      \
    _Pragma("unroll") for (int q = 0; q < 16; ++q)                             \
        P[q] = base0[(size_t)(TILE) * 8192 + q * 128];

#define K4_STAGE(P, BUF)                                                       \
    {                                                                          \
        short8 lo, hi;                                                         \
        _Pragma("unroll") for (int q = 0; q < 8; ++q) {                        \
            lo[q] = (short)f2bf(P[q]);                                         \
            hi[q] = (short)f2bf(P[q + 8]);                                     \
        }                                                                      \
        *(short8*)&Bt[BUF][kk * 72 + jg * 16] = lo;                            \
        *(short8*)&Bt[BUF][kk * 72 + jg * 16 + 8] = hi;                        \
    }

#define K4_COMPUTE(BUF, S)                                                     \
    _Pragma("unroll") for (int sub = 0; sub < 2; ++sub) {                      \
        short8 bf[8];                                                          \
        _Pragma("unroll") for (int nt = 0; nt < 8; ++nt)                       \
            bf[nt] = *(const short8*)&Bt[BUF][(nt * 16 + l15) * 72 + sub * 32 + l4 * 8]; \
        short8 af[2];                                                          \
        _Pragma("unroll") for (int mt = 0; mt < 2; ++mt) {                     \
            int ii = wave * 32 + mt * 16 + l15;                                \
            af[mt] = *(const short8*)(Xc + (size_t)ii * FEAT + (S) * 64 + sub * 32 + l4 * 8); \
        }                                                                      \
        _Pragma("unroll") for (int mt = 0; mt < 2; ++mt)                       \
            _Pragma("unroll") for (int nt = 0; nt < 8; ++nt)                   \
                acc[mt][nt] = __builtin_amdgcn_mfma_f32_16x16x32_bf16(         \
                    af[mt], bf[nt], acc[mt][nt], 0, 0, 0);                     \
    }

    float pA[16], pB[16];
    K4_ISSUE(pA, 0);
    K4_ISSUE(pB, 1);

    for (int it = 0; it < 21; ++it) {
        // tile 2it -> buffer 0
        K4_STAGE(pA, 0);
        bar_nd();
        if (it < 20) { K4_ISSUE(pA, 2 * it + 2); }
        K4_COMPUTE(0, 2 * it);
        // tile 2it+1 -> buffer 1
        K4_STAGE(pB, 1);
        bar_nd();
        if (it < 20) { K4_ISSUE(pB, 2 * it + 3); }
        K4_COMPUTE(1, 2 * it + 1);
    }
#undef K4_ISSUE
#undef K4_STAGE
#undef K4_COMPUTE

    // store T2[i][h][k] (transposed: i-major). 64 B chunks per quarter-wave.
#pragma unroll
    for (int mt = 0; mt < 2; ++mt)
#pragma unroll
        for (int nt = 0; nt < 8; ++nt) {
            int row0 = wave * 32 + mt * 16 + l4 * 4;
            int col = nt * 16 + l15;
#pragma unroll
            for (int rr = 0; rr < 4; ++rr)
                T2[(size_t)(row0 + rr) * 32768 + (size_t)h * 128 + col] =
                    acc[mt][nt][rr];
        }
}

// ---------------- K5: X[i,k] = fcb[i,k] + sum_h Hfc[i,h]*T2[i,h,k] ---------
// Block per i streams its contiguous 128 KB T2 row with float4 loads.
__global__ __launch_bounds__(512) void k5_stage2(const float* __restrict__ T2,
                                                 const float* __restrict__ Hfc,
                                                 const float* __restrict__ fcb,
                                                 float* __restrict__ X) {
    int i = blockIdx.x, t = threadIdx.x;   // 512 threads = 8 waves
    __shared__ float hrow[256];
    __shared__ __align__(16) float part[16][128];
    if (t < 256) hrow[t] = Hfc[(size_t)i * 256 + t];
    __syncthreads();
    int kq = t & 31;       // float4 index: k = kq*4
    int hs = t >> 5;       // h-slice 0..15, each covers 16 h
    f32x4 a;
    a[0] = 0.f; a[1] = 0.f; a[2] = 0.f; a[3] = 0.f;
    const float* tp = T2 + ((size_t)i * 256 + hs * 16) * 128 + kq * 4;
#pragma unroll
    for (int hh = 0; hh < 16; ++hh) {
        f32x4 tv = *(const f32x4*)(tp + (size_t)hh * 128);
        float w = hrow[hs * 16 + hh];
        a[0] += w * tv[0]; a[1] += w * tv[1]; a[2] += w * tv[2]; a[3] += w * tv[3];
    }
    *(f32x4*)&part[hs][kq * 4] = a;
    __syncthreads();
    if (t < 128) {
        float s = fcb[(size_t)i * 128 + t];
#pragma unroll
        for (int q = 0; q < 16; ++q) s += part[q][t];
        X[(size_t)i * 128 + t] = s;
    }
}

// ---------------- K6: bn2 (per-column over batch) + relu -> Xn (bf16) ------
__global__ void k6_bn2(const float* __restrict__ X, ushort* __restrict__ Xn) {
    int k = blockIdx.x;      // 128 blocks: one per column
    int i = threadIdx.x;     // 256 threads: one per row
    __shared__ float s1[256], s2[256];
    float v = X[i * 128 + k];
    s1[i] = v; s2[i] = v * v;
    __syncthreads();
    for (int s = 128; s > 0; s >>= 1) {
        if (i < s) { s1[i] += s1[i + s]; s2[i] += s2[i + s]; }
        __syncthreads();
    }
    float m = s1[0] / 256.f;
    float var = s2[0] / 256.f - m * m;
    float rstd = rsqrtf(var + EPS);
    Xn[i * 128 + k] = f2bf(fmaxf((v - m) * rstd, 0.f));
}

// ---------------- K7: out = sigmoid(Xn @ E2^T + b) -------------------------
// E2 slab staged+converted ONCE per block into padded LDS.
__global__ __launch_bounds__(256) void k7_final(const ushort* __restrict__ Xn,
                                                const float* __restrict__ E2,
                                                const float* __restrict__ bias,
                                                float* __restrict__ out) {
    int eb = blockIdx.x * 64;
    int t = threadIdx.x;
    int lane = t & 63, wave = t >> 6;
    int l15 = lane & 15, l4 = lane >> 4;
    int i0 = wave * 64;

    __shared__ __align__(16) ushort Eb[64][136];   // 64 ents x 128 bf16, +8 pad

    {
        int ent = t >> 2;
        int off = (t & 3) * 32;
        int e = eb + ent;
        const f32x4* rp4 = (const f32x4*)(E2 + (size_t)(e < NE ? e : NE - 1) * 128 + off);
#pragma unroll
        for (int q = 0; q < 8; ++q) {
            f32x4 v = rp4[q];
            uint u01 = (uint)f2bf(v[0]) | ((uint)f2bf(v[1]) << 16);
            uint u23 = (uint)f2bf(v[2]) | ((uint)f2bf(v[3]) << 16);
            uint2 w; w.x = u01; w.y = u23;
            *(uint2*)&Eb[ent][off + q * 4] = w;
        }
    }
    __syncthreads();

    f32x4 acc[4][4];
#pragma unroll
    for (int mt = 0; mt < 4; ++mt)
#pragma unroll
        for (int nt = 0; nt < 4; ++nt)
#pragma unroll
            for (int q = 0; q < 4; ++q) acc[mt][nt][q] = 0.f;

#pragma unroll
    for (int ks = 0; ks < 4; ++ks) {
        int k0 = ks * 32 + l4 * 8;
        short8 a[4];
#pragma unroll
        for (int mt = 0; mt < 4; ++mt) {
            int i = i0 + mt * 16 + l15;
            a[mt] = *(const short8*)(Xn + (size_t)i * 128 + k0);
        }
        short8 b[4];
#pragma unroll
        for (int nt = 0; nt < 4; ++nt)
            b[nt] = *(const short8*)&Eb[nt * 16 + l15][k0];
#pragma unroll
        for (int mt = 0; mt < 4; ++mt)
#pragma unroll
            for (int nt = 0; nt < 4; ++nt)
                acc[mt][nt] = __builtin_amdgcn_mfma_f32_16x16x32_bf16(
                    a[mt], b[nt], acc[mt][nt], 0, 0, 0);
    }
#pragma unroll
    for (int nt = 0; nt < 4; ++nt) {
        int e = eb + nt * 16 + l15;
        bool ok = e < NE;
        float bb = bias[e < NE ? e : NE - 1];
#pragma unroll
        for (int mt = 0; mt < 4; ++mt) {
            int row0 = i0 + mt * 16 + l4 * 4;
#pragma unroll
            for (int rr = 0; rr < 4; ++rr) {
                float v = acc[mt][nt][rr] + bb;
                float sg = 1.f / (1.f + __expf(-v));
                if (ok) out[(size_t)(row0 + rr) * NE + e] = sg;
            }
        }
    }
}

extern "C" void kernel_launch(void* const* d_in, const int* in_sizes, int n_in,
                              void* d_out, int out_size, void* d_ws, size_t ws_size,
                              hipStream_t stream) {
    const int* e1 = (const int*)d_in[0];
    const int* r = (const int*)d_in[1];
    const float* emb = (const float*)d_in[2];
    const float* rel = (const float*)d_in[3];
    const float* convw_w1 = (const float*)d_in[4];
    const float* convw_w2 = (const float*)d_in[5];
    const float* convb_w1 = (const float*)d_in[6];
    const float* convb_w2 = (const float*)d_in[7];
    const float* fcw_w1 = (const float*)d_in[8];
    const float* fcw_w2 = (const float*)d_in[9];
    const float* fcb_w1 = (const float*)d_in[10];
    const float* fcb_w2 = (const float*)d_in[11];
    const float* bvec = (const float*)d_in[12];
    float* out = (float*)d_out;

    char* ws = (char*)d_ws;
    float* stats = (float*)(ws + 0);            // 2 floats
    float* H = (float*)(ws + 256);              // [4][256][256] f32
    float* filt = (float*)(ws + 1048832);       // [256][288] f32
    float* cbias = (float*)(ws + 1343744);      // [256][32] f32
    float* fcbv = (float*)(ws + 1376512);       // [256][128] f32
    ushort* Xc = (ushort*)(ws + 1507584);       // [256][2688] bf16
    float* T2 = (float*)(ws + 2883840);         // [256 i][256 h][128 k] f32 (33.5 MB)
    float* X = (float*)(ws + 36438272);         // [256][128] f32
    ushort* Xn = (ushort*)(ws + 36569344);      // [256][128] bf16

    k0_bn0<<<1, 1024, 0, stream>>>(e1, emb, stats);
    k1_hidden<<<64, 256, 0, stream>>>(r, rel, convw_w1, convb_w1, fcw_w1, fcb_w1, H);
    k2_heads<<<32, 512, 0, stream>>>(H, convw_w2, convb_w2, fcb_w2, filt, cbias, fcbv);
    k3_conv<<<256, 256, 0, stream>>>(e1, emb, stats, filt, cbias, Xc);
    k4_gemm<<<256, 512, 0, stream>>>(Xc, fcw_w2, T2);
    k5_stage2<<<256, 512, 0, stream>>>(T2, H + 2 * 65536, fcbv, X);
    k6_bn2<<<128, 256, 0, stream>>>(X, Xn);
    k7_final<<<640, 256, 0, stream>>>(Xn, emb, bvec, out);
}

// Round 4
// 618.322 us; speedup vs baseline: 1.0248x; 1.0248x over previous
//
#include <hip/hip_runtime.h>
#include <cstdint>
#include <cstddef>

#define BATCH 256
#define ED 128
#define NC 32
#define FEAT 2688          // 32*6*14
#define HID 256
#define NE 40943
#define EPS 1e-5f
#define W2COLS 344064      // FEAT*128

typedef __attribute__((ext_vector_type(4))) float f32x4;
typedef __attribute__((ext_vector_type(8))) short short8;

__device__ __forceinline__ ushort f2bf(float f) {
    uint32_t u = __builtin_bit_cast(uint32_t, f);
    u = (u + 0x7FFFu + ((u >> 16) & 1u)) >> 16;
    return (ushort)u;
}

// Barrier WITHOUT the compiler's vmcnt(0) drain (k4 only; no global_load_lds).
__device__ __forceinline__ void bar_nd() {
    asm volatile("s_waitcnt lgkmcnt(0)" ::: "memory");
    __builtin_amdgcn_s_barrier();
    asm volatile("" ::: "memory");
}

// ================= kA: fused bn0 + CPG hidden + CPG heads + conv ==========
// 256 blocks (1 per sample) x 256 threads. NO grid sync: bn0 stats computed
// redundantly per block from L2-hot gathered rows; all other deps per-sample.
__global__ __launch_bounds__(256) void kA(
        const int* __restrict__ e1, const int* __restrict__ r,
        const float* __restrict__ emb, const float* __restrict__ rel,
        const float* __restrict__ w1a, const float* __restrict__ w1b,
        const float* __restrict__ w1c, const float* __restrict__ w1d,
        const float* __restrict__ w2f, const float* __restrict__ w2b,
        const float* __restrict__ w2fcb,
        float* __restrict__ Hfc, float* __restrict__ fcbv,
        ushort* __restrict__ Xc) {
    int b = blockIdx.x, t = threadIdx.x;
    __shared__ float Rs[128];
    __shared__ __align__(16) float Hs[4][256];
    __shared__ float red1[4], red2[4], smv[2];
    __shared__ float sfilt[288], scb[32], sx[128];

    // ---- Phase A: bn0 stats over all 256 gathered rows (redundant/block) --
    {
        float s1 = 0.f, s2 = 0.f;
        for (int it = 0; it < 128; ++it) {
            int idx = t + it * 256;
            int row = idx >> 7, col = idx & 127;
            float v = emb[(size_t)e1[row] * ED + col];
            s1 += v; s2 += v * v;
        }
#pragma unroll
        for (int off = 32; off > 0; off >>= 1) {
            s1 += __shfl_down(s1, off, 64);
            s2 += __shfl_down(s2, off, 64);
        }
        int lane = t & 63, wv = t >> 6;
        if (lane == 0) { red1[wv] = s1; red2[wv] = s2; }
        __syncthreads();
        if (t == 0) {
            float sa = red1[0] + red1[1] + red1[2] + red1[3];
            float sb = red2[0] + red2[1] + red2[2] + red2[3];
            float m = sa / 32768.f;
            float v = sb / 32768.f - m * m;
            smv[0] = m;
            smv[1] = rsqrtf(v + EPS);
        }
    }

    // ---- Phase B: hidden for sample b, all 4 heads ----
    int rv = r[b];
    if (t < 128) Rs[t] = rel[(size_t)rv * 128 + t];
    __syncthreads();
    {
        float a0 = 0.f, a1 = 0.f, a2 = 0.f, a3 = 0.f;
        for (int d4 = 0; d4 < 32; ++d4) {
            int d = d4 * 4;
            f32x4 rr = *(const f32x4*)&Rs[d];
#pragma unroll
            for (int j = 0; j < 4; ++j) {
                int o = (d + j) * 256 + t;
                a0 = fmaf(rr[j], w1a[o], a0);
                a1 = fmaf(rr[j], w1b[o], a1);
                a2 = fmaf(rr[j], w1c[o], a2);
                a3 = fmaf(rr[j], w1d[o], a3);
            }
        }
        float h0 = fmaxf(a0, 0.f), h1 = fmaxf(a1, 0.f);
        float h2 = fmaxf(a2, 0.f), h3 = fmaxf(a3, 0.f);
        Hs[0][t] = h0; Hs[1][t] = h1; Hs[2][t] = h2; Hs[3][t] = h3;
        Hfc[(size_t)b * 256 + t] = h2;          // fcw hidden -> global for k5
    }
    __syncthreads();

    // ---- Phase C: head outputs (448 of them, 2 passes of 256 threads) ----
#pragma unroll
    for (int pass = 0; pass < 2; ++pass) {
        int tt = t + pass * 256;
        if (tt < 448) {
            const float* hb;
            const float* wp;
            int st;
            if (tt < 288)      { hb = &Hs[0][0]; wp = w2f + tt;          st = 288; }
            else if (tt < 320) { hb = &Hs[1][0]; wp = w2b + (tt - 288);  st = 32;  }
            else               { hb = &Hs[3][0]; wp = w2fcb + (tt - 320); st = 128; }
            float acc = 0.f;
            for (int u4 = 0; u4 < 64; ++u4) {
                int uu = u4 * 4;
                f32x4 hv = *(const f32x4*)&hb[uu];
                acc = fmaf(hv[0], wp[(uu + 0) * st],
                      fmaf(hv[1], wp[(uu + 1) * st],
                      fmaf(hv[2], wp[(uu + 2) * st],
                      fmaf(hv[3], wp[(uu + 3) * st], acc))));
            }
            if (tt < 288)      sfilt[tt] = acc;
            else if (tt < 320) scb[tt - 288] = acc;
            else               fcbv[(size_t)b * 128 + (tt - 320)] = acc;
        }
    }
    // normalize input row for conv (needs smv from Phase A)
    if (t < 128) sx[t] = (emb[(size_t)e1[b] * ED + t] - smv[0]) * smv[1];
    __syncthreads();

    // ---- Phase D: conv + bias + relu -> Xc (bf16) ----
    for (int o = t; o < FEAT; o += 256) {
        int c = o / 84, rem = o % 84;          // 84 = 6*14
        int y = rem / 14, xw = rem % 14;
        float acc = scb[c];
        const float* fc = &sfilt[c * 9];
#pragma unroll
        for (int dy = 0; dy < 3; ++dy)
#pragma unroll
            for (int dx = 0; dx < 3; ++dx)
                acc += sx[(y + dy) * 16 + (xw + dx)] * fc[dy * 3 + dx];
        Xc[(size_t)b * FEAT + o] = f2bf(fmaxf(acc, 0.f));
    }
}

// ================= K4: big batched GEMM (unchanged, measured-good) =========
__global__ __launch_bounds__(512, 2) void k4_gemm(const ushort* __restrict__ Xc,
                                                  const float* __restrict__ W2,
                                                  float* __restrict__ T2) {
    int h = blockIdx.x;
    int tid = threadIdx.x, lane = tid & 63, wave = tid >> 6;   // 8 waves
    int l15 = lane & 15, l4 = lane >> 4;
    __shared__ __align__(16) ushort Bt[2][128 * 72];   // [buf][k=128][j=64 +8 pad]
    const float* Brow = W2 + (size_t)h * W2COLS;

    int kk = tid & 127;
    int jg = tid >> 7;

    f32x4 acc[2][8];
#pragma unroll
    for (int mt = 0; mt < 2; ++mt)
#pragma unroll
        for (int nt = 0; nt < 8; ++nt)
#pragma unroll
            for (int q = 0; q < 4; ++q) acc[mt][nt][q] = 0.f;

    const float* base0 = Brow + (size_t)jg * 16 * 128 + kk;

#define K4_ISSUE(P, TILE)                                                      \
    _Pragma("unroll") for (int q = 0; q < 16; ++q)                             \
        P[q] = base0[(size_t)(TILE) * 8192 + q * 128];

#define K4_STAGE(P, BUF)                                                       \
    {                                                                          \
        short8 lo, hi;                                                         \
        _Pragma("unroll") for (int q = 0; q < 8; ++q) {                        \
            lo[q] = (short)f2bf(P[q]);                                         \
            hi[q] = (short)f2bf(P[q + 8]);                                     \
        }                                                                      \
        *(short8*)&Bt[BUF][kk * 72 + jg * 16] = lo;                            \
        *(short8*)&Bt[BUF][kk * 72 + jg * 16 + 8] = hi;                        \
    }

#define K4_COMPUTE(BUF, S)                                                     \
    _Pragma("unroll") for (int sub = 0; sub < 2; ++sub) {                      \
        short8 bf[8];                                                          \
        _Pragma("unroll") for (int nt = 0; nt < 8; ++nt)                       \
            bf[nt] = *(const short8*)&Bt[BUF][(nt * 16 + l15) * 72 + sub * 32 + l4 * 8]; \
        short8 af[2];                                                          \
        _Pragma("unroll") for (int mt = 0; mt < 2; ++mt) {                     \
            int ii = wave * 32 + mt * 16 + l15;                                \
            af[mt] = *(const short8*)(Xc + (size_t)ii * FEAT + (S) * 64 + sub * 32 + l4 * 8); \
        }                                                                      \
        _Pragma("unroll") for (int mt = 0; mt < 2; ++mt)                       \
            _Pragma("unroll") for (int nt = 0; nt < 8; ++nt)                   \
                acc[mt][nt] = __builtin_amdgcn_mfma_f32_16x16x32_bf16(         \
                    af[mt], bf[nt], acc[mt][nt], 0, 0, 0);                     \
    }

    float pA[16], pB[16];
    K4_ISSUE(pA, 0);
    K4_ISSUE(pB, 1);

    for (int it = 0; it < 21; ++it) {
        K4_STAGE(pA, 0);
        bar_nd();
        if (it < 20) { K4_ISSUE(pA, 2 * it + 2); }
        K4_COMPUTE(0, 2 * it);
        K4_STAGE(pB, 1);
        bar_nd();
        if (it < 20) { K4_ISSUE(pB, 2 * it + 3); }
        K4_COMPUTE(1, 2 * it + 1);
    }
#undef K4_ISSUE
#undef K4_STAGE
#undef K4_COMPUTE

#pragma unroll
    for (int mt = 0; mt < 2; ++mt)
#pragma unroll
        for (int nt = 0; nt < 8; ++nt) {
            int row0 = wave * 32 + mt * 16 + l4 * 4;
            int col = nt * 16 + l15;
#pragma unroll
            for (int rr = 0; rr < 4; ++rr)
                T2[(size_t)(row0 + rr) * 32768 + (size_t)h * 128 + col] =
                    acc[mt][nt][rr];
        }
}

// ================= K5: X[i,k] = fcb[i,k] + sum_h Hfc[i,h]*T2[i,h,k] ========
__global__ __launch_bounds__(512) void k5_stage2(const float* __restrict__ T2,
                                                 const float* __restrict__ Hfc,
                                                 const float* __restrict__ fcb,
                                                 float* __restrict__ X) {
    int i = blockIdx.x, t = threadIdx.x;   // 512 threads = 8 waves
    __shared__ float hrow[256];
    __shared__ __align__(16) float part[16][128];
    if (t < 256) hrow[t] = Hfc[(size_t)i * 256 + t];
    __syncthreads();
    int kq = t & 31;       // float4 index: k = kq*4
    int hs = t >> 5;       // h-slice 0..15, each covers 16 h
    f32x4 a;
    a[0] = 0.f; a[1] = 0.f; a[2] = 0.f; a[3] = 0.f;
    const float* tp = T2 + ((size_t)i * 256 + hs * 16) * 128 + kq * 4;
#pragma unroll
    for (int hh = 0; hh < 16; ++hh) {
        f32x4 tv = *(const f32x4*)(tp + (size_t)hh * 128);
        float w = hrow[hs * 16 + hh];
        a[0] += w * tv[0]; a[1] += w * tv[1]; a[2] += w * tv[2]; a[3] += w * tv[3];
    }
    *(f32x4*)&part[hs][kq * 4] = a;
    __syncthreads();
    if (t < 128) {
        float s = fcb[(size_t)i * 128 + t];
#pragma unroll
        for (int q = 0; q < 16; ++q) s += part[q][t];
        X[(size_t)i * 128 + t] = s;
    }
}

// ================= k67: fused bn2 + final sigmoid GEMM =====================
// 640 blocks x 256 threads. Each block recomputes bn2 column stats from X
// (128 KB, L2-hot, deterministic -> identical in every block), then does the
// MFMA with on-the-fly normalize+relu+bf16-convert of A-fragments.
__global__ __launch_bounds__(256) void k67_final(const float* __restrict__ X,
                                                 const float* __restrict__ E2,
                                                 const float* __restrict__ bias,
                                                 float* __restrict__ out) {
    int eb = blockIdx.x * 64;
    int t = threadIdx.x;
    int lane = t & 63, wave = t >> 6;
    int l15 = lane & 15, l4 = lane >> 4;
    int i0 = wave * 64;

    __shared__ __align__(16) ushort Eb[64][136];   // 64 ents x 128 bf16, +8 pad
    __shared__ float cs1[256], cs2[256];
    __shared__ __align__(16) float meanL[128], rstdL[128];

    // ---- bn2 column stats (redundant per block) ----
    {
        int col = t & 127, hf = t >> 7;
        float s1 = 0.f, s2 = 0.f;
        const float* xp = X + (size_t)(hf * 128) * 128 + col;
#pragma unroll 8
        for (int rr = 0; rr < 128; ++rr) {
            float v = xp[(size_t)rr * 128];
            s1 += v; s2 += v * v;
        }
        cs1[t] = s1; cs2[t] = s2;
    }

    // ---- stage E2 slab -> bf16 LDS (overlaps stats in issue order) ----
    {
        int ent = t >> 2;
        int off = (t & 3) * 32;
        int e = eb + ent;
        const f32x4* rp4 = (const f32x4*)(E2 + (size_t)(e < NE ? e : NE - 1) * 128 + off);
#pragma unroll
        for (int q = 0; q < 8; ++q) {
            f32x4 v = rp4[q];
            uint u01 = (uint)f2bf(v[0]) | ((uint)f2bf(v[1]) << 16);
            uint u23 = (uint)f2bf(v[2]) | ((uint)f2bf(v[3]) << 16);
            uint2 w; w.x = u01; w.y = u23;
            *(uint2*)&Eb[ent][off + q * 4] = w;
        }
    }
    __syncthreads();
    if (t < 128) {
        float a = cs1[t] + cs1[t + 128];
        float b = cs2[t] + cs2[t + 128];
        float m = a / 256.f;
        float var = b / 256.f - m * m;
        meanL[t] = m;
        rstdL[t] = rsqrtf(var + EPS);
    }
    __syncthreads();

    f32x4 acc[4][4];
#pragma unroll
    for (int mt = 0; mt < 4; ++mt)
#pragma unroll
        for (int nt = 0; nt < 4; ++nt)
#pragma unroll
            for (int q = 0; q < 4; ++q) acc[mt][nt][q] = 0.f;

#pragma unroll
    for (int ks = 0; ks < 4; ++ks) {
        int k0 = ks * 32 + l4 * 8;
        f32x4 mv0 = *(const f32x4*)&meanL[k0];
        f32x4 mv1 = *(const f32x4*)&meanL[k0 + 4];
        f32x4 rv0 = *(const f32x4*)&rstdL[k0];
        f32x4 rv1 = *(const f32x4*)&rstdL[k0 + 4];
        short8 a[4];
#pragma unroll
        for (int mt = 0; mt < 4; ++mt) {
            int i = i0 + mt * 16 + l15;
            const f32x4* xp = (const f32x4*)(X + (size_t)i * 128 + k0);
            f32x4 x0 = xp[0], x1 = xp[1];
            short8 av;
#pragma unroll
            for (int q = 0; q < 4; ++q) {
                av[q]     = (short)f2bf(fmaxf((x0[q] - mv0[q]) * rv0[q], 0.f));
                av[q + 4] = (short)f2bf(fmaxf((x1[q] - mv1[q]) * rv1[q], 0.f));
            }
            a[mt] = av;
        }
        short8 bfr[4];
#pragma unroll
        for (int nt = 0; nt < 4; ++nt)
            bfr[nt] = *(const short8*)&Eb[nt * 16 + l15][k0];
#pragma unroll
        for (int mt = 0; mt < 4; ++mt)
#pragma unroll
            for (int nt = 0; nt < 4; ++nt)
                acc[mt][nt] = __builtin_amdgcn_mfma_f32_16x16x32_bf16(
                    a[mt], bfr[nt], acc[mt][nt], 0, 0, 0);
    }
#pragma unroll
    for (int nt = 0; nt < 4; ++nt) {
        int e = eb + nt * 16 + l15;
        bool ok = e < NE;
        float bb = bias[e < NE ? e : NE - 1];
#pragma unroll
        for (int mt = 0; mt < 4; ++mt) {
            int row0 = i0 + mt * 16 + l4 * 4;
#pragma unroll
            for (int rr = 0; rr < 4; ++rr) {
                float v = acc[mt][nt][rr] + bb;
                float sg = 1.f / (1.f + __expf(-v));
                if (ok) out[(size_t)(row0 + rr) * NE + e] = sg;
            }
        }
    }
}

extern "C" void kernel_launch(void* const* d_in, const int* in_sizes, int n_in,
                              void* d_out, int out_size, void* d_ws, size_t ws_size,
                              hipStream_t stream) {
    const int* e1 = (const int*)d_in[0];
    const int* r = (const int*)d_in[1];
    const float* emb = (const float*)d_in[2];
    const float* rel = (const float*)d_in[3];
    const float* convw_w1 = (const float*)d_in[4];
    const float* convw_w2 = (const float*)d_in[5];
    const float* convb_w1 = (const float*)d_in[6];
    const float* convb_w2 = (const float*)d_in[7];
    const float* fcw_w1 = (const float*)d_in[8];
    const float* fcw_w2 = (const float*)d_in[9];
    const float* fcb_w1 = (const float*)d_in[10];
    const float* fcb_w2 = (const float*)d_in[11];
    const float* bvec = (const float*)d_in[12];
    float* out = (float*)d_out;

    char* ws = (char*)d_ws;
    float* Hfc = (float*)(ws + 0);              // [256][256] f32 (fcw hidden)
    float* fcbv = (float*)(ws + 262144);        // [256][128] f32
    ushort* Xc = (ushort*)(ws + 393216);        // [256][2688] bf16
    float* T2 = (float*)(ws + 1769472);         // [256 i][256 h][128 k] f32
    float* X = (float*)(ws + 35323904);         // [256][128] f32

    {
        kA<<<256, 256, 0, stream>>>(e1, r, emb, rel,
                                    convw_w1, convb_w1, fcw_w1, fcb_w1,
                                    convw_w2, convb_w2, fcb_w2,
                                    Hfc, fcbv, Xc);
    }
    k4_gemm<<<256, 512, 0, stream>>>(Xc, fcw_w2, T2);
    k5_stage2<<<256, 512, 0, stream>>>(T2, Hfc, fcbv, X);
    k67_final<<<640, 256, 0, stream>>>(X, emb, bvec, out);
}

// Round 6
// 617.118 us; speedup vs baseline: 1.0268x; 1.0020x over previous
//
#include <hip/hip_runtime.h>
#include <cstdint>
#include <cstddef>

#define BATCH 256
#define ED 128
#define NC 32
#define FEAT 2688          // 32*6*14
#define HID 256
#define NE 40943
#define EPS 1e-5f
#define W2COLS 344064      // FEAT*128

typedef __attribute__((ext_vector_type(4))) float f32x4;
typedef __attribute__((ext_vector_type(8))) short short8;

__device__ __forceinline__ ushort f2bf(float f) {
    uint32_t u = __builtin_bit_cast(uint32_t, f);
    u = (u + 0x7FFFu + ((u >> 16) & 1u)) >> 16;
    return (ushort)u;
}

// Barrier WITHOUT the compiler's vmcnt(0) drain (k4 only; no global_load_lds).
__device__ __forceinline__ void bar_nd() {
    asm volatile("s_waitcnt lgkmcnt(0)" ::: "memory");
    __builtin_amdgcn_s_barrier();
    asm volatile("" ::: "memory");
}

// ================= kA: fused bn0 + CPG hidden + CPG heads + conv ==========
// 256 blocks (1 per sample) x 256 threads. NO grid sync: bn0 stats computed
// redundantly per block from L2-hot gathered rows; all other deps per-sample.
__global__ __launch_bounds__(256) void kA(
        const int* __restrict__ e1, const int* __restrict__ r,
        const float* __restrict__ emb, const float* __restrict__ rel,
        const float* __restrict__ w1a, const float* __restrict__ w1b,
        const float* __restrict__ w1c, const float* __restrict__ w1d,
        const float* __restrict__ w2f, const float* __restrict__ w2b,
        const float* __restrict__ w2fcb,
        float* __restrict__ Hfc, float* __restrict__ fcbv,
        ushort* __restrict__ Xc) {
    int b = blockIdx.x, t = threadIdx.x;
    __shared__ float Rs[128];
    __shared__ __align__(16) float Hs[4][256];
    __shared__ float red1[4], red2[4], smv[2];
    __shared__ float sfilt[288], scb[32], sx[128];

    // ---- Phase A: bn0 stats over all 256 gathered rows (redundant/block) --
    {
        float s1 = 0.f, s2 = 0.f;
        for (int it = 0; it < 128; ++it) {
            int idx = t + it * 256;
            int row = idx >> 7, col = idx & 127;
            float v = emb[(size_t)e1[row] * ED + col];
            s1 += v; s2 += v * v;
        }
#pragma unroll
        for (int off = 32; off > 0; off >>= 1) {
            s1 += __shfl_down(s1, off, 64);
            s2 += __shfl_down(s2, off, 64);
        }
        int lane = t & 63, wv = t >> 6;
        if (lane == 0) { red1[wv] = s1; red2[wv] = s2; }
        __syncthreads();
        if (t == 0) {
            float sa = red1[0] + red1[1] + red1[2] + red1[3];
            float sb = red2[0] + red2[1] + red2[2] + red2[3];
            float m = sa / 32768.f;
            float v = sb / 32768.f - m * m;
            smv[0] = m;
            smv[1] = rsqrtf(v + EPS);
        }
    }

    // ---- Phase B: hidden for sample b, all 4 heads ----
    int rv = r[b];
    if (t < 128) Rs[t] = rel[(size_t)rv * 128 + t];
    __syncthreads();
    {
        float a0 = 0.f, a1 = 0.f, a2 = 0.f, a3 = 0.f;
        for (int d4 = 0; d4 < 32; ++d4) {
            int d = d4 * 4;
            f32x4 rr = *(const f32x4*)&Rs[d];
#pragma unroll
            for (int j = 0; j < 4; ++j) {
                int o = (d + j) * 256 + t;
                a0 = fmaf(rr[j], w1a[o], a0);
                a1 = fmaf(rr[j], w1b[o], a1);
                a2 = fmaf(rr[j], w1c[o], a2);
                a3 = fmaf(rr[j], w1d[o], a3);
            }
        }
        float h0 = fmaxf(a0, 0.f), h1 = fmaxf(a1, 0.f);
        float h2 = fmaxf(a2, 0.f), h3 = fmaxf(a3, 0.f);
        Hs[0][t] = h0; Hs[1][t] = h1; Hs[2][t] = h2; Hs[3][t] = h3;
        Hfc[(size_t)b * 256 + t] = h2;          // fcw hidden -> global for k5
    }
    __syncthreads();

    // ---- Phase C: head outputs (448 of them, 2 passes of 256 threads) ----
#pragma unroll
    for (int pass = 0; pass < 2; ++pass) {
        int tt = t + pass * 256;
        if (tt < 448) {
            const float* hb;
            const float* wp;
            int st;
            if (tt < 288)      { hb = &Hs[0][0]; wp = w2f + tt;          st = 288; }
            else if (tt < 320) { hb = &Hs[1][0]; wp = w2b + (tt - 288);  st = 32;  }
            else               { hb = &Hs[3][0]; wp = w2fcb + (tt - 320); st = 128; }
            float acc = 0.f;
            for (int u4 = 0; u4 < 64; ++u4) {
                int uu = u4 * 4;
                f32x4 hv = *(const f32x4*)&hb[uu];
                acc = fmaf(hv[0], wp[(uu + 0) * st],
                      fmaf(hv[1], wp[(uu + 1) * st],
                      fmaf(hv[2], wp[(uu + 2) * st],
                      fmaf(hv[3], wp[(uu + 3) * st], acc))));
            }
            if (tt < 288)      sfilt[tt] = acc;
            else if (tt < 320) scb[tt - 288] = acc;
            else               fcbv[(size_t)b * 128 + (tt - 320)] = acc;
        }
    }
    // normalize input row for conv (needs smv from Phase A)
    if (t < 128) sx[t] = (emb[(size_t)e1[b] * ED + t] - smv[0]) * smv[1];
    __syncthreads();

    // ---- Phase D: conv + bias + relu -> Xc (bf16) ----
    for (int o = t; o < FEAT; o += 256) {
        int c = o / 84, rem = o % 84;          // 84 = 6*14
        int y = rem / 14, xw = rem % 14;
        float acc = scb[c];
        const float* fc = &sfilt[c * 9];
#pragma unroll
        for (int dy = 0; dy < 3; ++dy)
#pragma unroll
            for (int dx = 0; dx < 3; ++dx)
                acc += sx[(y + dy) * 16 + (xw + dx)] * fc[dy * 3 + dx];
        Xc[(size_t)b * FEAT + o] = f2bf(fmaxf(acc, 0.f));
    }
}

// ================= K4: big batched GEMM, depth-4 register prefetch =========
// One block per h (256 blocks); W2 row streamed from HBM exactly once.
// 42 tiles of 64 j-columns. LDS double-buffer, ONE no-drain barrier per
// phase. Prefetch distance = 4 tiles (~1400 cyc) via 4 rotating register
// sets pA..pD. 42 = 4*10 + 2: main loop 10 iters x 4 tiles, tail 2 tiles.
__global__ __launch_bounds__(512, 2) void k4_gemm(const ushort* __restrict__ Xc,
                                                  const float* __restrict__ W2,
                                                  float* __restrict__ T2) {
    int h = blockIdx.x;
    int tid = threadIdx.x, lane = tid & 63, wave = tid >> 6;   // 8 waves
    int l15 = lane & 15, l4 = lane >> 4;
    __shared__ __align__(16) ushort Bt[2][128 * 72];   // [buf][k=128][j=64 +8 pad]
    const float* Brow = W2 + (size_t)h * W2COLS;

    int kk = tid & 127;        // k index this thread stages
    int jg = tid >> 7;         // j-group (0..3): 16 j's per group within 64-j tile

    f32x4 acc[2][8];
#pragma unroll
    for (int mt = 0; mt < 2; ++mt)
#pragma unroll
        for (int nt = 0; nt < 8; ++nt)
#pragma unroll
            for (int q = 0; q < 4; ++q) acc[mt][nt][q] = 0.f;

    const float* base0 = Brow + (size_t)jg * 16 * 128 + kk;

// TILE in [0,42): 64 j-columns each (8192 floats of W2 row).
#define K4_ISSUE(P, TILE)                                                      \
    _Pragma("unroll") for (int q = 0; q < 16; ++q)                             \
        P[q] = base0[(size_t)(TILE) * 8192 + q * 128];

#define K4_STAGE(P, BUF)                                                       \
    {                                                                          \
        short8 lo, hi;                                                         \
        _Pragma("unroll") for (int q = 0; q < 8; ++q) {                        \
            lo[q] = (short)f2bf(P[q]);                                         \
            hi[q] = (short)f2bf(P[q + 8]);                                     \
        }                                                                      \
        *(short8*)&Bt[BUF][kk * 72 + jg * 16] = lo;                            \
        *(short8*)&Bt[BUF][kk * 72 + jg * 16 + 8] = hi;                        \
    }

#define K4_COMPUTE(BUF, S)                                                     \
    _Pragma("unroll") for (int sub = 0; sub < 2; ++sub) {                      \
        short8 bf[8];                                                          \
        _Pragma("unroll") for (int nt = 0; nt < 8; ++nt)                       \
            bf[nt] = *(const short8*)&Bt[BUF][(nt * 16 + l15) * 72 + sub * 32 + l4 * 8]; \
        short8 af[2];                                                          \
        _Pragma("unroll") for (int mt = 0; mt < 2; ++mt) {                     \
            int ii = wave * 32 + mt * 16 + l15;                                \
            af[mt] = *(const short8*)(Xc + (size_t)ii * FEAT + (S) * 64 + sub * 32 + l4 * 8); \
        }                                                                      \
        _Pragma("unroll") for (int mt = 0; mt < 2; ++mt)                       \
            _Pragma("unroll") for (int nt = 0; nt < 8; ++nt)                   \
                acc[mt][nt] = __builtin_amdgcn_mfma_f32_16x16x32_bf16(         \
                    af[mt], bf[nt], acc[mt][nt], 0, 0, 0);                     \
    }

    float pA[16], pB[16], pC[16], pD[16];
    K4_ISSUE(pA, 0);
    K4_ISSUE(pB, 1);
    K4_ISSUE(pC, 2);
    K4_ISSUE(pD, 3);

    for (int it = 0; it < 10; ++it) {
        // tile 4it   (pA) -> buffer 0; refill pA 4 ahead
        K4_STAGE(pA, 0);
        bar_nd();
        K4_ISSUE(pA, 4 * it + 4);               // max 40
        K4_COMPUTE(0, 4 * it);
        // tile 4it+1 (pB) -> buffer 1
        K4_STAGE(pB, 1);
        bar_nd();
        K4_ISSUE(pB, 4 * it + 5);               // max 41
        K4_COMPUTE(1, 4 * it + 1);
        // tile 4it+2 (pC) -> buffer 0
        K4_STAGE(pC, 0);
        bar_nd();
        if (it < 9) { K4_ISSUE(pC, 4 * it + 6); }   // max 42 excluded
        K4_COMPUTE(0, 4 * it + 2);
        // tile 4it+3 (pD) -> buffer 1
        K4_STAGE(pD, 1);
        bar_nd();
        if (it < 9) { K4_ISSUE(pD, 4 * it + 7); }
        K4_COMPUTE(1, 4 * it + 3);
    }
    // tail: tiles 40 (pA), 41 (pB)
    K4_STAGE(pA, 0);
    bar_nd();
    K4_COMPUTE(0, 40);
    K4_STAGE(pB, 1);
    bar_nd();
    K4_COMPUTE(1, 41);
#undef K4_ISSUE
#undef K4_STAGE
#undef K4_COMPUTE

    // store T2[i][h][k] (transposed: i-major). 64 B chunks per quarter-wave.
#pragma unroll
    for (int mt = 0; mt < 2; ++mt)
#pragma unroll
        for (int nt = 0; nt < 8; ++nt) {
            int row0 = wave * 32 + mt * 16 + l4 * 4;
            int col = nt * 16 + l15;
#pragma unroll
            for (int rr = 0; rr < 4; ++rr)
                T2[(size_t)(row0 + rr) * 32768 + (size_t)h * 128 + col] =
                    acc[mt][nt][rr];
        }
}

// ================= K5: X[i,k] = fcb[i,k] + sum_h Hfc[i,h]*T2[i,h,k] ========
__global__ __launch_bounds__(512) void k5_stage2(const float* __restrict__ T2,
                                                 const float* __restrict__ Hfc,
                                                 const float* __restrict__ fcb,
                                                 float* __restrict__ X) {
    int i = blockIdx.x, t = threadIdx.x;   // 512 threads = 8 waves
    __shared__ float hrow[256];
    __shared__ __align__(16) float part[16][128];
    if (t < 256) hrow[t] = Hfc[(size_t)i * 256 + t];
    __syncthreads();
    int kq = t & 31;       // float4 index: k = kq*4
    int hs = t >> 5;       // h-slice 0..15, each covers 16 h
    f32x4 a;
    a[0] = 0.f; a[1] = 0.f; a[2] = 0.f; a[3] = 0.f;
    const float* tp = T2 + ((size_t)i * 256 + hs * 16) * 128 + kq * 4;
#pragma unroll
    for (int hh = 0; hh < 16; ++hh) {
        f32x4 tv = *(const f32x4*)(tp + (size_t)hh * 128);
        float w = hrow[hs * 16 + hh];
        a[0] += w * tv[0]; a[1] += w * tv[1]; a[2] += w * tv[2]; a[3] += w * tv[3];
    }
    *(f32x4*)&part[hs][kq * 4] = a;
    __syncthreads();
    if (t < 128) {
        float s = fcb[(size_t)i * 128 + t];
#pragma unroll
        for (int q = 0; q < 16; ++q) s += part[q][t];
        X[(size_t)i * 128 + t] = s;
    }
}

// ================= k67: fused bn2 + final sigmoid GEMM =====================
// 640 blocks x 256 threads. Each block recomputes bn2 column stats from X
// (128 KB, L2-hot, deterministic -> identical in every block), then does the
// MFMA with on-the-fly normalize+relu+bf16-convert of A-fragments.
__global__ __launch_bounds__(256) void k67_final(const float* __restrict__ X,
                                                 const float* __restrict__ E2,
                                                 const float* __restrict__ bias,
                                                 float* __restrict__ out) {
    int eb = blockIdx.x * 64;
    int t = threadIdx.x;
    int lane = t & 63, wave = t >> 6;
    int l15 = lane & 15, l4 = lane >> 4;
    int i0 = wave * 64;

    __shared__ __align__(16) ushort Eb[64][136];   // 64 ents x 128 bf16, +8 pad
    __shared__ float cs1[256], cs2[256];
    __shared__ __align__(16) float meanL[128], rstdL[128];

    // ---- bn2 column stats (redundant per block) ----
    {
        int col = t & 127, hf = t >> 7;
        float s1 = 0.f, s2 = 0.f;
        const float* xp = X + (size_t)(hf * 128) * 128 + col;
#pragma unroll 8
        for (int rr = 0; rr < 128; ++rr) {
            float v = xp[(size_t)rr * 128];
            s1 += v; s2 += v * v;
        }
        cs1[t] = s1; cs2[t] = s2;
    }

    // ---- stage E2 slab -> bf16 LDS ----
    {
        int ent = t >> 2;
        int off = (t & 3) * 32;
        int e = eb + ent;
        const f32x4* rp4 = (const f32x4*)(E2 + (size_t)(e < NE ? e : NE - 1) * 128 + off);
#pragma unroll
        for (int q = 0; q < 8; ++q) {
            f32x4 v = rp4[q];
            uint u01 = (uint)f2bf(v[0]) | ((uint)f2bf(v[1]) << 16);
            uint u23 = (uint)f2bf(v[2]) | ((uint)f2bf(v[3]) << 16);
            uint2 w; w.x = u01; w.y = u23;
            *(uint2*)&Eb[ent][off + q * 4] = w;
        }
    }
    __syncthreads();
    if (t < 128) {
        float a = cs1[t] + cs1[t + 128];
        float b = cs2[t] + cs2[t + 128];
        float m = a / 256.f;
        float var = b / 256.f - m * m;
        meanL[t] = m;
        rstdL[t] = rsqrtf(var + EPS);
    }
    __syncthreads();

    f32x4 acc[4][4];
#pragma unroll
    for (int mt = 0; mt < 4; ++mt)
#pragma unroll
        for (int nt = 0; nt < 4; ++nt)
#pragma unroll
            for (int q = 0; q < 4; ++q) acc[mt][nt][q] = 0.f;

#pragma unroll
    for (int ks = 0; ks < 4; ++ks) {
        int k0 = ks * 32 + l4 * 8;
        f32x4 mv0 = *(const f32x4*)&meanL[k0];
        f32x4 mv1 = *(const f32x4*)&meanL[k0 + 4];
        f32x4 rv0 = *(const f32x4*)&rstdL[k0];
        f32x4 rv1 = *(const f32x4*)&rstdL[k0 + 4];
        short8 a[4];
#pragma unroll
        for (int mt = 0; mt < 4; ++mt) {
            int i = i0 + mt * 16 + l15;
            const f32x4* xp = (const f32x4*)(X + (size_t)i * 128 + k0);
            f32x4 x0 = xp[0], x1 = xp[1];
            short8 av;
#pragma unroll
            for (int q = 0; q < 4; ++q) {
                av[q]     = (short)f2bf(fmaxf((x0[q] - mv0[q]) * rv0[q], 0.f));
                av[q + 4] = (short)f2bf(fmaxf((x1[q] - mv1[q]) * rv1[q], 0.f));
            }
            a[mt] = av;
        }
        short8 bfr[4];
#pragma unroll
        for (int nt = 0; nt < 4; ++nt)
            bfr[nt] = *(const short8*)&Eb[nt * 16 + l15][k0];
#pragma unroll
        for (int mt = 0; mt < 4; ++mt)
#pragma unroll
            for (int nt = 0; nt < 4; ++nt)
                acc[mt][nt] = __builtin_amdgcn_mfma_f32_16x16x32_bf16(
                    a[mt], bfr[nt], acc[mt][nt], 0, 0, 0);
    }
#pragma unroll
    for (int nt = 0; nt < 4; ++nt) {
        int e = eb + nt * 16 + l15;
        bool ok = e < NE;
        float bb = bias[e < NE ? e : NE - 1];
#pragma unroll
        for (int mt = 0; mt < 4; ++mt) {
            int row0 = i0 + mt * 16 + l4 * 4;
#pragma unroll
            for (int rr = 0; rr < 4; ++rr) {
                float v = acc[mt][nt][rr] + bb;
                float sg = 1.f / (1.f + __expf(-v));
                if (ok) out[(size_t)(row0 + rr) * NE + e] = sg;
            }
        }
    }
}

extern "C" void kernel_launch(void* const* d_in, const int* in_sizes, int n_in,
                              void* d_out, int out_size, void* d_ws, size_t ws_size,
                              hipStream_t stream) {
    const int* e1 = (const int*)d_in[0];
    const int* r = (const int*)d_in[1];
    const float* emb = (const float*)d_in[2];
    const float* rel = (const float*)d_in[3];
    const float* convw_w1 = (const float*)d_in[4];
    const float* convw_w2 = (const float*)d_in[5];
    const float* convb_w1 = (const float*)d_in[6];
    const float* convb_w2 = (const float*)d_in[7];
    const float* fcw_w1 = (const float*)d_in[8];
    const float* fcw_w2 = (const float*)d_in[9];
    const float* fcb_w1 = (const float*)d_in[10];
    const float* fcb_w2 = (const float*)d_in[11];
    const float* bvec = (const float*)d_in[12];
    float* out = (float*)d_out;

    char* ws = (char*)d_ws;
    float* Hfc = (float*)(ws + 0);              // [256][256] f32 (fcw hidden)
    float* fcbv = (float*)(ws + 262144);        // [256][128] f32
    ushort* Xc = (ushort*)(ws + 393216);        // [256][2688] bf16
    float* T2 = (float*)(ws + 1769472);         // [256 i][256 h][128 k] f32
    float* X = (float*)(ws + 35323904);         // [256][128] f32

    kA<<<256, 256, 0, stream>>>(e1, r, emb, rel,
                                convw_w1, convb_w1, fcw_w1, fcb_w1,
                                convw_w2, convb_w2, fcb_w2,
                                Hfc, fcbv, Xc);
    k4_gemm<<<256, 512, 0, stream>>>(Xc, fcw_w2, T2);
    k5_stage2<<<256, 512, 0, stream>>>(T2, Hfc, fcbv, X);
    k67_final<<<640, 256, 0, stream>>>(X, emb, bvec, out);
}